// Round 2
// baseline (129.572 us; speedup 1.0000x reference)
//
#include <hip/hip_runtime.h>

#define NB 4096
#define SS 102
#define SSP 104    // q rows padded to a multiple of 4
#define HID 8      // HIDDEN
#define NH 2       // HEADS
#define HD 4       // HEAD_DIM

typedef float v2f __attribute__((ext_vector_type(2)));

// LDS layout:
//  sRaw : [3][102][8] raw q/k/v rows; first 816 floats reused for the
//         head-combined attention output before the wo projection
//  sQ   : [2][104][4] rotated+pre-scaled q (rows 102,103 zero pad)
//  sK   : [2][102][4] rotated k
//  sV   : [2][102][4] projected v
//  sW   : [4][64] wq, wk, wv, wo
__global__ __launch_bounds__(256, 4) void mha_fused_kernel(
    const float* __restrict__ query, const float* __restrict__ key,
    const float* __restrict__ value, const float* __restrict__ wq,
    const float* __restrict__ wk, const float* __restrict__ wv,
    const float* __restrict__ wo, float* __restrict__ out)
{
    __shared__ float sRaw[3 * SS * HID];     // 2448
    __shared__ float sQ[NH * SSP * HD];      // 832
    __shared__ float sK[NH * SS * HD];       // 816
    __shared__ float sV[NH * SS * HD];       // 816
    __shared__ float sW[4 * 64];             // 256

    const int t = threadIdx.x;
    const int b = blockIdx.x;

    // ---- weights ----
    if (t < 64)        sW[t] = wq[t];
    else if (t < 128)  sW[t] = wk[t - 64];
    else if (t < 192)  sW[t] = wv[t - 128];
    else               sW[t] = wo[t - 192];

    // ---- zero-pad q rows 102,103 (both heads): 2*2*4 = 16 floats ----
    if (t >= 208 && t < 224) {
        const int z = t - 208;                // 0..15
        const int h = z >> 3, r = SS + ((z >> 2) & 1), d = z & 3;
        sQ[h * SSP * HD + r * HD + d] = 0.f;
    }

    // ---- stage raw inputs, coalesced float4 ----
    {
        const float4* q4 = (const float4*)(query + (size_t)b * (SS * HID));
        const float4* k4 = (const float4*)(key   + (size_t)b * (SS * HID));
        const float4* v4 = (const float4*)(value + (size_t)b * (SS * HID));
        float4* sRaw4 = (float4*)sRaw;
        if (t < 204) {
            sRaw4[t]       = q4[t];
            sRaw4[204 + t] = k4[t];
            sRaw4[408 + t] = v4[t];
        }
    }
    __syncthreads();

    // ---- q/k projection + fused rotary ----
    // reference broadcast quirk: head 0 scaled by sin(s), head 1 by cos(s);
    // rotary pair: out_even=(x_even-x_odd)*w, out_odd=(x_odd+x_even)*w.
    // For q we also fold in 0.5 (score scale) * log2(e) so the softmax can
    // use raw v_exp_f32 (base-2) with no per-tuple argument multiply.
    for (int p = t; p < 816; p += 256) {
        const int tensor = p / 408;          // 0 = q, 1 = k
        const int pp = p % 408;
        const int s  = pp >> 2;
        const int pr = pp & 3;
        const int i0 = pr * 2, i1 = i0 + 1;
        const float* raw = sRaw + tensor * (SS * HID) + s * HID;
        const float* w   = sW + tensor * 64;
        float x0 = 0.f, x1 = 0.f;
#pragma unroll
        for (int j = 0; j < 8; ++j) {
            x0 += raw[j] * w[i0 * 8 + j];
            x1 += raw[j] * w[i1 * 8 + j];
        }
        const int h = i0 >> 2;
        float wr = (h == 0) ? sinf((float)s) : cosf((float)s);
        if (tensor == 0) wr *= 0.72134752044448170368f;  // 0.5 * log2(e)
        const float r0 = (x0 - x1) * wr;
        const float r1 = (x1 + x0) * wr;
        const int d0 = i0 & 3;
        float* dst = (tensor == 0)
            ? (sQ + h * SSP * HD + s * HD + d0)
            : (sK + h * SS * HD + s * HD + d0);
        dst[0] = r0;
        dst[1] = r1;
    }
    // ---- v projection ----
    for (int e = t; e < 816; e += 256) {
        const int s = e >> 3, i = e & 7;
        const float* raw = sRaw + 2 * (SS * HID) + s * HID;
        const float* w   = sW + 2 * 64 + i * 8;
        float x = 0.f;
#pragma unroll
        for (int j = 0; j < 8; ++j) x += raw[j] * w[j];
        const int h = i >> 2, d = i & 3;
        sV[h * SS * HD + s * HD + d] = x;
    }
    __syncthreads();

    // ---- attention: wave 0 only; each thread owns 4 q-rows of one head.
    // lanes 0..25 -> head 0 rows 4t..4t+3 ; lanes 32..57 -> head 1.
    // K/V rows are read once per iteration and amortized over 4 q-rows;
    // row-pairs processed as float2 so the compiler can emit v_pk_fma_f32.
    const int h  = (t >= 32) ? 1 : 0;
    const int tb = t - h * 32;
    const bool active = (t < 58) && (tb < 26);
    v2f acc01[4] = {}, acc23[4] = {};
    v2f l01 = {0.f, 0.f}, l23 = {0.f, 0.f};
    if (active) {
        const float* qb = sQ + h * SSP * HD + (4 * tb) * HD;
        const float4 qa = ((const float4*)qb)[0];
        const float4 qB = ((const float4*)qb)[1];
        const float4 qc = ((const float4*)qb)[2];
        const float4 qd = ((const float4*)qb)[3];
        v2f q01[4] = {{qa.x, qB.x}, {qa.y, qB.y}, {qa.z, qB.z}, {qa.w, qB.w}};
        v2f q23[4] = {{qc.x, qd.x}, {qc.y, qd.y}, {qc.z, qd.z}, {qc.w, qd.w}};
        const float4* K4 = (const float4*)(sK + h * SS * HD);
        const float4* V4 = (const float4*)(sV + h * SS * HD);
        for (int k = 0; k < SS; ++k) {
            const float4 kk = K4[k];
            const float4 vv = V4[k];
            v2f s01 = q01[0] * kk.x + q01[1] * kk.y + q01[2] * kk.z + q01[3] * kk.w;
            v2f s23 = q23[0] * kk.x + q23[1] * kk.y + q23[2] * kk.z + q23[3] * kk.w;
            v2f p01, p23;
            p01.x = __builtin_amdgcn_exp2f(s01.x);
            p01.y = __builtin_amdgcn_exp2f(s01.y);
            p23.x = __builtin_amdgcn_exp2f(s23.x);
            p23.y = __builtin_amdgcn_exp2f(s23.y);
            l01 += p01; l23 += p23;
            acc01[0] += p01 * vv.x; acc01[1] += p01 * vv.y;
            acc01[2] += p01 * vv.z; acc01[3] += p01 * vv.w;
            acc23[0] += p23 * vv.x; acc23[1] += p23 * vv.y;
            acc23[2] += p23 * vv.z; acc23[3] += p23 * vv.w;
        }
    }
    __syncthreads();   // order: projection reads of sRaw done before reuse
    if (active) {
        const float l[4] = {l01.x, l01.y, l23.x, l23.y};
#pragma unroll
        for (int j = 0; j < 4; ++j) {
            const int row = 4 * tb + j;
            if (row < SS) {
                const float inv = 1.f / l[j];
                float* comb = sRaw + row * HID + h * HD;
                const v2f* accp = (j < 2) ? acc01 : acc23;
                const int c = j & 1;
                comb[0] = accp[0][c] * inv;
                comb[1] = accp[1][c] * inv;
                comb[2] = accp[2][c] * inv;
                comb[3] = accp[3][c] * inv;
            }
        }
    }
    __syncthreads();

    // ---- output projection (wo) + coalesced store ----
    for (int e = t; e < 816; e += 256) {
        const int s = e >> 3, i = e & 7;
        const float* comb = sRaw + s * HID;
        const float* w    = sW + 3 * 64 + i * 8;
        float x = 0.f;
#pragma unroll
        for (int j = 0; j < 8; ++j) x += comb[j] * w[j];
        out[(size_t)b * (SS * HID) + e] = x;
    }
}

extern "C" void kernel_launch(void* const* d_in, const int* in_sizes, int n_in,
                              void* d_out, int out_size, void* d_ws, size_t ws_size,
                              hipStream_t stream) {
    const float* query = (const float*)d_in[0];
    const float* key   = (const float*)d_in[1];
    const float* value = (const float*)d_in[2];
    const float* wq    = (const float*)d_in[3];
    const float* wk    = (const float*)d_in[4];
    const float* wv    = (const float*)d_in[5];
    const float* wo    = (const float*)d_in[6];
    float* out = (float*)d_out;
    mha_fused_kernel<<<NB, 256, 0, stream>>>(query, key, value, wq, wk, wv, wo, out);
}

// Round 3
// 118.585 us; speedup vs baseline: 1.0926x; 1.0926x over previous
//
#include <hip/hip_runtime.h>

#define NB 4096
#define SS 102
#define SSP 104    // q rows padded to a multiple of 2 lanes*2
#define HID 8      // HIDDEN
#define NH 2       // HEADS
#define HD 4       // HEAD_DIM

typedef float v2f __attribute__((ext_vector_type(2)));

// LDS layout:
//  sRaw : [3][102][8] raw q/k/v rows.
//         After the projections this region is dead and is reused:
//           [0..816)    head-combined attention output (comb)
//           [816..1856) cross-wave attention partials [h][row][5]
//  sQ   : [2][104][4] rotated+pre-scaled q (rows 102,103 zero pad)
//  sK   : [2][102][4] rotated k
//  sV   : [2][102][4] projected v
//  sW   : [4][64] wq, wk, wv, wo
//  sRot : sin(s) at [0..102), cos(s) at [102..204)
__global__ __launch_bounds__(256) void mha_fused_kernel(
    const float* __restrict__ query, const float* __restrict__ key,
    const float* __restrict__ value, const float* __restrict__ wq,
    const float* __restrict__ wk, const float* __restrict__ wv,
    const float* __restrict__ wo, float* __restrict__ out)
{
    __shared__ float sRaw[3 * SS * HID];     // 2448
    __shared__ float sQ[NH * SSP * HD];      // 832
    __shared__ float sK[NH * SS * HD];       // 816
    __shared__ float sV[NH * SS * HD];       // 816
    __shared__ float sW[4 * 64];             // 256
    __shared__ float sRot[2 * SS];           // 204

    const int t = threadIdx.x;
    const int b = blockIdx.x;

    // ---- issue all global loads into registers first ----
    float4 rq, rk, rv;
    if (t < 204) {
        const float4* q4 = (const float4*)(query + (size_t)b * (SS * HID));
        const float4* k4 = (const float4*)(key   + (size_t)b * (SS * HID));
        const float4* v4 = (const float4*)(value + (size_t)b * (SS * HID));
        rq = q4[t]; rk = k4[t]; rv = v4[t];
    }
    float wreg;
    {
        const float* wsrc = (t < 64) ? wq : (t < 128) ? wk : (t < 192) ? wv : wo;
        wreg = wsrc[t & 63];
    }

    // ---- sin/cos table: overlaps the global-load latency (no data dep) ----
    if (t < SS)                    sRot[t] = sinf((float)t);
    else if (t >= 128 && t < 230)  sRot[SS + (t - 128)] = cosf((float)(t - 128));

    // ---- zero-pad q rows 102,103 (both heads) ----
    if (t >= 230 && t < 246) {
        const int z = t - 230;                // 0..15
        const int h = z >> 3, r = SS + ((z >> 2) & 1), d = z & 3;
        sQ[h * SSP * HD + r * HD + d] = 0.f;
    }

    // ---- commit staged data to LDS ----
    sW[t] = wreg;
    if (t < 204) {
        float4* sRaw4 = (float4*)sRaw;
        sRaw4[t]       = rq;
        sRaw4[204 + t] = rk;
        sRaw4[408 + t] = rv;
    }
    __syncthreads();

    // ---- q/k projection + fused rotary (816 pair-items) ----
    // reference broadcast quirk: head 0 scaled by sin(s), head 1 by cos(s);
    // rotary pair: out_even=(x_even-x_odd)*w, out_odd=(x_odd+x_even)*w.
    // q additionally folds 0.5 (score scale) * log2(e) so softmax can use
    // raw v_exp_f32 (base-2).
    for (int p = t; p < 816; p += 256) {
        const int tensor = (p >= 408) ? 1 : 0;   // 0 = q, 1 = k (no div)
        const int pp = tensor ? (p - 408) : p;
        const int s  = pp >> 2;
        const int pr = pp & 3;
        const int i0 = pr * 2, i1 = i0 + 1;
        const float4* raw4 = (const float4*)(sRaw + tensor * (SS * HID) + s * HID);
        const float4 ra = raw4[0], rb = raw4[1];
        const float4* w0 = (const float4*)(sW + tensor * 64 + i0 * 8);
        const float4 wa = w0[0], wb = w0[1], wc = w0[2], wd = w0[3];
        float x0 = ra.x * wa.x + ra.y * wa.y + ra.z * wa.z + ra.w * wa.w
                 + rb.x * wb.x + rb.y * wb.y + rb.z * wb.z + rb.w * wb.w;
        float x1 = ra.x * wc.x + ra.y * wc.y + ra.z * wc.z + ra.w * wc.w
                 + rb.x * wd.x + rb.y * wd.y + rb.z * wd.z + rb.w * wd.w;
        const int h = pr >> 1;
        float wr = sRot[h * SS + s];
        if (tensor == 0) wr *= 0.72134752044448170368f;  // 0.5 * log2(e)
        const float r0 = (x0 - x1) * wr;
        const float r1 = (x1 + x0) * wr;
        const int d0 = i0 & 3;
        float* dst = (tensor == 0)
            ? (sQ + h * SSP * HD + s * HD + d0)
            : (sK + h * SS * HD + s * HD + d0);
        dst[0] = r0;
        dst[1] = r1;
    }
    // ---- v projection ----
    for (int e = t; e < 816; e += 256) {
        const int s = e >> 3, i = e & 7;
        const float4* raw4 = (const float4*)(sRaw + 2 * (SS * HID) + s * HID);
        const float4 ra = raw4[0], rb = raw4[1];
        const float4* w0 = (const float4*)(sW + 2 * 64 + i * 8);
        const float4 wa = w0[0], wb = w0[1];
        const float x = ra.x * wa.x + ra.y * wa.y + ra.z * wa.z + ra.w * wa.w
                      + rb.x * wb.x + rb.y * wb.y + rb.z * wb.z + rb.w * wb.w;
        const int h = i >> 2, d = i & 3;
        sV[h * SS * HD + s * HD + d] = x;
    }
    __syncthreads();

    // ---- attention: ALL 4 waves. wave = h*2 + khalf.
    // Each wave handles one head and one half of the k range (51 keys).
    // Each lane owns 2 q-rows (52 active lanes -> 104 padded rows),
    // packed as float2 so the compiler can emit v_pk_fma_f32.
    const int wv_  = t >> 6, lane = t & 63;
    const int h    = wv_ >> 1;
    const int kh   = wv_ & 1;
    const bool act = lane < 52;
    v2f acc0 = {0.f, 0.f}, acc1 = {0.f, 0.f}, acc2 = {0.f, 0.f}, acc3 = {0.f, 0.f};
    v2f l = {0.f, 0.f};
    if (act) {
        const float* qb = sQ + h * SSP * HD + (2 * lane) * HD;
        const float4 qa = ((const float4*)qb)[0];
        const float4 qc = ((const float4*)qb)[1];
        const v2f q0 = {qa.x, qc.x}, q1 = {qa.y, qc.y},
                  q2 = {qa.z, qc.z}, q3 = {qa.w, qc.w};
        const float4* K4 = (const float4*)(sK + h * SS * HD) + kh * 51;
        const float4* V4 = (const float4*)(sV + h * SS * HD) + kh * 51;
        // register-rotating prefetch: load k+1 while computing k
        float4 kk = K4[0], vvv = V4[0];
#pragma unroll 2
        for (int k = 1; k < 51; ++k) {
            const float4 nk = K4[k], nv = V4[k];
            v2f s = q0 * kk.x + q1 * kk.y + q2 * kk.z + q3 * kk.w;
            v2f p;
            p.x = __builtin_amdgcn_exp2f(s.x);
            p.y = __builtin_amdgcn_exp2f(s.y);
            l += p;
            acc0 += p * vvv.x; acc1 += p * vvv.y;
            acc2 += p * vvv.z; acc3 += p * vvv.w;
            kk = nk; vvv = nv;
        }
        {
            v2f s = q0 * kk.x + q1 * kk.y + q2 * kk.z + q3 * kk.w;
            v2f p;
            p.x = __builtin_amdgcn_exp2f(s.x);
            p.y = __builtin_amdgcn_exp2f(s.y);
            l += p;
            acc0 += p * vvv.x; acc1 += p * vvv.y;
            acc2 += p * vvv.z; acc3 += p * vvv.w;
        }
    }
    // khalf=1 publishes partials into the dead sRaw region [816..1856).
    // (raw-input reads all completed before the previous barrier)
    if (act && kh == 1) {
        float* part = sRaw + 816 + (h * SSP + 2 * lane) * 5;
        part[0] = acc0.x; part[1] = acc1.x; part[2] = acc2.x;
        part[3] = acc3.x; part[4] = l.x;
        part[5] = acc0.y; part[6] = acc1.y; part[7] = acc2.y;
        part[8] = acc3.y; part[9] = l.y;
    }
    __syncthreads();
    // khalf=0 combines, normalizes, writes head-combined rows
    if (act && kh == 0) {
        const float* part = sRaw + 816 + (h * SSP + 2 * lane) * 5;
        const float a0[2] = {acc0.x, acc0.y}, a1[2] = {acc1.x, acc1.y};
        const float a2[2] = {acc2.x, acc2.y}, a3[2] = {acc3.x, acc3.y};
        const float ll[2] = {l.x, l.y};
#pragma unroll
        for (int j = 0; j < 2; ++j) {
            const int row = 2 * lane + j;
            if (row < SS) {
                const float s0 = a0[j] + part[5 * j + 0];
                const float s1 = a1[j] + part[5 * j + 1];
                const float s2 = a2[j] + part[5 * j + 2];
                const float s3 = a3[j] + part[5 * j + 3];
                const float L  = ll[j] + part[5 * j + 4];
                const float inv = 1.f / L;
                float* comb = sRaw + row * HID + h * HD;
                comb[0] = s0 * inv; comb[1] = s1 * inv;
                comb[2] = s2 * inv; comb[3] = s3 * inv;
            }
        }
    }
    __syncthreads();

    // ---- output projection (wo) + coalesced store ----
    for (int e = t; e < 816; e += 256) {
        const int s = e >> 3, i = e & 7;
        const float4* c4 = (const float4*)(sRaw + s * HID);
        const float4 ca = c4[0], cb = c4[1];
        const float4* w0 = (const float4*)(sW + 3 * 64 + i * 8);
        const float4 wa = w0[0], wb = w0[1];
        const float x = ca.x * wa.x + ca.y * wa.y + ca.z * wa.z + ca.w * wa.w
                      + cb.x * wb.x + cb.y * wb.y + cb.z * wb.z + cb.w * wb.w;
        out[(size_t)b * (SS * HID) + e] = x;
    }
}

extern "C" void kernel_launch(void* const* d_in, const int* in_sizes, int n_in,
                              void* d_out, int out_size, void* d_ws, size_t ws_size,
                              hipStream_t stream) {
    const float* query = (const float*)d_in[0];
    const float* key   = (const float*)d_in[1];
    const float* value = (const float*)d_in[2];
    const float* wq    = (const float*)d_in[3];
    const float* wk    = (const float*)d_in[4];
    const float* wv    = (const float*)d_in[5];
    const float* wo    = (const float*)d_in[6];
    float* out = (float*)d_out;
    mha_fused_kernel<<<NB, 256, 0, stream>>>(query, key, value, wq, wk, wv, wo, out);
}